// Round 8
// baseline (2172.117 us; speedup 1.0000x reference)
//
#include <hip/hip_runtime.h>
#include <math.h>

#define N_RES 768
#define DS 384
#define DP 128
#define DH 16
#define NH 12
#define PQ 4
#define PV 8
#define HC (NH*DH)              // 192
#define CATD (NH*(DP+DH+PV*4))  // 2112
#define NSPLIT 2
#define KRANGE (N_RES/NSPLIT)   // 384
#define BK 32
#define ZP 132                  // padded z row; near-free banks (R1-measured)
#define PSTRIDE 2048            // partial: m12|s12|o192@24|opts288@216|opair1536@504

// ws float offsets
#define WS_Q    0                               // [768][192]
#define WS_KT   (WS_Q    + N_RES*HC)            // [12*16][768]
#define WS_V    (WS_KT   + NH*DH*N_RES)         // [768][192]
#define WS_QP   (WS_V    + N_RES*HC)            // [768][144]
#define WS_KPT  (WS_QP   + N_RES*NH*PQ*3)       // [12*12][768]
#define WS_VP   (WS_KPT  + NH*PQ*3*N_RES)       // [768][288]
#define WS_KPSQ (WS_VP   + N_RES*NH*PV*3)       // [12][768]
#define WS_WBT  (WS_KPSQ + NH*N_RES)            // [12][128]
#define WS_PART (WS_WBT  + NH*DP)               // [768*2][2048]
#define WS_CAT  (WS_PART + N_RES*NSPLIT*PSTRIDE)// [768][2112]

// ---------------- kernel 1: input projections + frame apply ----------------
__global__ __launch_bounds__(256) void k_proj(
    const float* __restrict__ s, const float* __restrict__ rot,
    const float* __restrict__ trans,
    const float* __restrict__ Wq, const float* __restrict__ bq,
    const float* __restrict__ Wkv, const float* __restrict__ bkv,
    const float* __restrict__ Wqp, const float* __restrict__ bqp,
    const float* __restrict__ Wkvp, const float* __restrict__ bkvp,
    const float* __restrict__ Wb,
    float* __restrict__ ws)
{
    __shared__ float s_s[8][DS];
    __shared__ float rq[8][NH*PQ*3];
    __shared__ float rkv[8][NH*(PQ+PV)*3];
    __shared__ float kpsq_s[8][NH];
    const int t = threadIdx.x;
    const int n0 = blockIdx.x * 8;

    for (int idx = t; idx < 8 * DS; idx += 256)
        s_s[idx / DS][idx % DS] = s[(n0 + idx / DS) * DS + idx % DS];
    if (t < 96) kpsq_s[t / 12][t % 12] = 0.f;
    if (blockIdx.x == 0) {      // WbT [h][c] for k_attn's L1-broadcast reads
        for (int i = t; i < DP * NH; i += 256)
            ws[WS_WBT + (i % NH) * DP + i / NH] = Wb[i];
    }
    __syncthreads();

    // 1152 output columns: [Wq 192 | Wkv 384 | Wqp 144 | Wkvp 432]
    for (int j = t; j < 1152; j += 256) {
        const float* W; int col, nc; float bias;
        if (j < 192)      { W = Wq;   col = j;       nc = 192; bias = bq[col]; }
        else if (j < 576) { W = Wkv;  col = j - 192; nc = 384; bias = bkv[col]; }
        else if (j < 720) { W = Wqp;  col = j - 576; nc = 144; bias = bqp[col]; }
        else              { W = Wkvp; col = j - 720; nc = 432; bias = bkvp[col]; }
        float acc[8];
        #pragma unroll
        for (int r = 0; r < 8; r++) acc[r] = bias;
        for (int i = 0; i < DS; i++) {
            float w = W[i * nc + col];
            #pragma unroll
            for (int r = 0; r < 8; r++) acc[r] += s_s[r][i] * w;
        }
        if (j < 192) {
            #pragma unroll
            for (int r = 0; r < 8; r++) ws[WS_Q + (size_t)(n0 + r) * HC + j] = acc[r];
        } else if (j < 576) {
            int jj = j - 192, h = jj / 32, dd = jj % 32;
            if (dd < 16) {  // K -> transposed [h*16+d][k]
                #pragma unroll
                for (int r = 0; r < 8; r++)
                    ws[WS_KT + (size_t)(h * DH + dd) * N_RES + (n0 + r)] = acc[r];
            } else {
                #pragma unroll
                for (int r = 0; r < 8; r++)
                    ws[WS_V + (size_t)(n0 + r) * HC + h * 16 + dd - 16] = acc[r];
            }
        } else if (j < 720) {
            #pragma unroll
            for (int r = 0; r < 8; r++) rq[r][j - 576] = acc[r];
        } else {
            #pragma unroll
            for (int r = 0; r < 8; r++) rkv[r][j - 720] = acc[r];
        }
    }
    __syncthreads();

    // frame apply: 8 rows * (48 qp + 144 kvp) points
    for (int idx = t; idx < 8 * 192; idx += 256) {
        int r = idx / 192, pi = idx % 192;
        int n = n0 + r;
        const float* R = rot + n * 9;
        const float* T = trans + n * 3;
        if (pi < 48) {
            float x = rq[r][pi], y = rq[r][48 + pi], zc = rq[r][96 + pi];
            float* dst = ws + WS_QP + (size_t)n * (NH * PQ * 3) + pi * 3;
            dst[0] = R[0] * x + R[1] * y + R[2] * zc + T[0];
            dst[1] = R[3] * x + R[4] * y + R[5] * zc + T[1];
            dst[2] = R[6] * x + R[7] * y + R[8] * zc + T[2];
        } else {
            int p2 = pi - 48;
            float x = rkv[r][p2], y = rkv[r][144 + p2], zc = rkv[r][288 + p2];
            int h = p2 / 12, pp = p2 % 12;
            float fx = R[0] * x + R[1] * y + R[2] * zc + T[0];
            float fy = R[3] * x + R[4] * y + R[5] * zc + T[1];
            float fz = R[6] * x + R[7] * y + R[8] * zc + T[2];
            if (pp < 4) {   // k_pts -> transposed [h*12 + p*3+c][k]
                size_t b = WS_KPT + (size_t)(h * 12 + pp * 3) * N_RES + n;
                ws[b] = fx; ws[b + N_RES] = fy; ws[b + 2 * N_RES] = fz;
                atomicAdd(&kpsq_s[r][h], fx * fx + fy * fy + fz * fz);
            } else {
                float* dst = ws + WS_VP + (size_t)n * (NH * PV * 3) + (h * PV + pp - 4) * 3;
                dst[0] = fx; dst[1] = fy; dst[2] = fz;
            }
        }
    }
    __syncthreads();
    if (t < 96)   // kpsq transposed [h][k] for coalesced k_attn reads
        ws[WS_KPSQ + (size_t)(t % 12) * N_RES + (n0 + t / 12)] = kpsq_s[t / 12][t % 12];
}

// ---------------- kernel 2: split-K fused IPA attention ----------------
// grid (q, ks) = 1536 blocks, 256 thr = 4 waves; wave w owns heads 3w..3w+2.
// BK=32 tile: 32 k-rows handled by 32-lane groups; the two wave halves split
// the bias-chunk (even/odd, 16B apart -> distinct banks) and the qk/pt d-range,
// combined with one shfl_xor(32). LDS ~20 KB; 2 barriers/tile.
__global__ __launch_bounds__(256) void k_attn(
    const float* __restrict__ zg, const float* __restrict__ mask,
    const float* __restrict__ bb, const float* __restrict__ hweights,
    float* __restrict__ ws)
{
    __shared__ float z_s[BK * ZP];      // 16.9 KB
    __shared__ float p_s[NH][33];       // stride 33: 3-head readers hit distinct banks
    __shared__ float q_s[HC];
    __shared__ float qph_s[NH * 12];
    __shared__ float r_s[NH];

    const int t = threadIdx.x;
    const int lane = t & 63;
    const int w = t >> 6;        // wave 0..3
    const int h0 = 3 * w;
    const int q  = blockIdx.x >> 1;
    const int ks = blockIdx.x & 1;
    const int kbase = ks * KRANGE;
    const int kl = lane & 31;
    const int half = lane >> 5;

    const float* zq = zg + ((size_t)q * N_RES + kbase) * DP;
    const float* wbt = ws + WS_WBT;

    for (int i = t; i < HC; i += 256)
        q_s[i] = ws[WS_Q + (size_t)q * HC + i] * 0.1443375673f;     // sqrt(1/48)
    for (int i = t; i < 144; i += 256) {
        float hwv = log1pf(expf(hweights[i / 12])) * 0.1360827635f; // softplus*sqrt(1/54)
        qph_s[i] = ws[WS_QP + (size_t)q * 144 + i] * hwv;           // + hw*(qp.kp) term
    }

    float hw3[3], bbv[3];
    #pragma unroll
    for (int hl = 0; hl < 3; hl++) {
        hw3[hl] = log1pf(expf(hweights[h0 + hl])) * 0.1360827635f;
        bbv[hl] = bb[h0 + hl];
    }

    float m_run[3], ssum[3], acc_z[3][2];
    #pragma unroll
    for (int hl = 0; hl < 3; hl++) {
        m_run[hl] = -1e30f; ssum[hl] = 0.f;
        acc_z[hl][0] = 0.f; acc_z[hl][1] = 0.f;
    }
    float acc_o = 0.f, acc_p0 = 0.f, acc_p1 = 0.f;

    const bool act_o = (lane < 48);
    const int h_o = h0 + (lane >> 4);          // deref only when act_o
    const int h_pA = h0 + lane / 24;
    const bool act_p1 = (lane < 8);

    for (int kb = 0; kb < KRANGE; kb += BK) {
        __syncthreads();   // prev tile's z_s/p_s consumers done (also covers setup)
        {
            const float4* src = (const float4*)(zq + (size_t)kb * DP);
            #pragma unroll
            for (int i = 0; i < 4; i++) {
                int idx = i * 256 + t;
                float4 v = src[idx];
                *(float4*)&z_s[(idx >> 5) * ZP + (idx & 31) * 4] = v;
            }
        }
        __syncthreads();   // tile staged

        const int kk = kbase + kb + kl;

        // ---- half-split partial logit: 0.577*(z.Wb) + qk + hw*(qp.kp) ----
        float part[3];
        {
            float bacc[3] = {0.f, 0.f, 0.f};
            #pragma unroll
            for (int c4 = 0; c4 < 16; c4++) {
                int chunk = c4 * 2 + half;       // even/odd: halves 16B apart
                float4 z4 = *(const float4*)&z_s[kl * ZP + chunk * 4];
                #pragma unroll
                for (int hl = 0; hl < 3; hl++) {
                    float4 w4 = *(const float4*)&wbt[(h0 + hl) * DP + chunk * 4];
                    bacc[hl] += z4.x * w4.x + z4.y * w4.y + z4.z * w4.z + z4.w * w4.w;
                }
            }
            #pragma unroll
            for (int hl = 0; hl < 3; hl++) part[hl] = bacc[hl] * 0.5773502692f;
        }
        #pragma unroll
        for (int hl = 0; hl < 3; hl++) {
            int gh = h0 + hl;
            const float* kt = ws + WS_KT + (size_t)(gh * DH + half * 8) * N_RES + kk;
            float dot = 0.f;
            #pragma unroll
            for (int dd = 0; dd < 8; dd++)
                dot += q_s[gh * 16 + half * 8 + dd] * kt[(size_t)dd * N_RES];
            const float* kpt = ws + WS_KPT + (size_t)(gh * 12 + half * 6) * N_RES + kk;
            #pragma unroll
            for (int cc = 0; cc < 6; cc++)
                dot += qph_s[gh * 12 + half * 6 + cc] * kpt[(size_t)cc * N_RES];
            part[hl] += dot;
        }
        float mval = mask[(size_t)q * N_RES + kk];
        float logit[3];
        #pragma unroll
        for (int hl = 0; hl < 3; hl++) {
            int gh = h0 + hl;
            float comb = part[hl] + __shfl_xor(part[hl], 32);
            logit[hl] = comb + mval + bbv[hl] * 0.5773502692f
                        - 0.5f * hw3[hl] * ws[WS_KPSQ + (size_t)gh * N_RES + kk];
        }

        // ---- online softmax over 32-group (halves hold identical values) ----
        float rloc[3];
        #pragma unroll
        for (int hl = 0; hl < 3; hl++) {
            float lm = logit[hl];
            #pragma unroll
            for (int off = 16; off; off >>= 1) lm = fmaxf(lm, __shfl_xor(lm, off));
            float m_new = fmaxf(m_run[hl], lm);
            float rr = __expf(m_run[hl] - m_new);
            float p = __expf(logit[hl] - m_new);
            ssum[hl] = ssum[hl] * rr + p;
            if (half == 0) p_s[h0 + hl][kl] = p;
            if (lane == 0) r_s[h0 + hl] = rr;
            rloc[hl] = rr;
            m_run[hl] = m_new;
        }
        // no barrier: p_s/r_s producers and consumers are the same wave

        // ---- o_pair from staged z (lane owns cols lane, 64+lane) ----
        #pragma unroll
        for (int hl = 0; hl < 3; hl++) { acc_z[hl][0] *= rloc[hl]; acc_z[hl][1] *= rloc[hl]; }
        #pragma unroll 4
        for (int j = 0; j < BK; j++) {
            float z0 = z_s[j * ZP + lane];
            float z1 = z_s[j * ZP + 64 + lane];
            #pragma unroll
            for (int hl = 0; hl < 3; hl++) {
                float pv = p_s[h0 + hl][j];
                acc_z[hl][0] += pv * z0;
                acc_z[hl][1] += pv * z1;
            }
        }

        // ---- o from V (coalesced 192B rows per wave) ----
        if (act_o) {
            acc_o *= r_s[h_o];
            const float* vbase = ws + WS_V + (size_t)(kbase + kb) * HC + w * 48 + lane;
            #pragma unroll 4
            for (int j = 0; j < BK; j++)
                acc_o += p_s[h_o][j] * vbase[(size_t)j * HC];
        }
        // ---- o_pts from VP (global frame) ----
        {
            acc_p0 *= r_s[h_pA];
            if (act_p1) acc_p1 *= r_s[h0 + 2];
            const float* vpb = ws + WS_VP + (size_t)(kbase + kb) * 288 + w * 72;
            #pragma unroll 4
            for (int j = 0; j < BK; j++) {
                const float* vr = vpb + (size_t)j * 288;
                acc_p0 += p_s[h_pA][j] * vr[lane];
                if (act_p1) acc_p1 += p_s[h0 + 2][j] * vr[64 + lane];
            }
        }
    }

    // ---- write unnormalized partials ----
    #pragma unroll
    for (int hl = 0; hl < 3; hl++) {
        float sv = ssum[hl];
        #pragma unroll
        for (int off = 16; off; off >>= 1) sv += __shfl_xor(sv, off);
        ssum[hl] = sv;
    }
    float* part = ws + WS_PART + (size_t)blockIdx.x * PSTRIDE;
    if (lane == 0) {
        #pragma unroll
        for (int hl = 0; hl < 3; hl++) {
            part[h0 + hl] = m_run[hl];
            part[12 + h0 + hl] = ssum[hl];
        }
    }
    if (act_o) part[24 + w * 48 + lane] = acc_o;
    part[216 + w * 72 + lane] = acc_p0;
    if (act_p1) part[216 + w * 72 + 64 + lane] = acc_p1;
    #pragma unroll
    for (int hl = 0; hl < 3; hl++) {
        part[504 + (h0 + hl) * 128 + lane] = acc_z[hl][0];
        part[504 + (h0 + hl) * 128 + 64 + lane] = acc_z[hl][1];
    }
}

// ---------------- kernel 3: merge 2 partials + epilogue ----------------
__global__ __launch_bounds__(256) void k_merge(
    const float* __restrict__ rot, const float* __restrict__ trans,
    float* __restrict__ ws)
{
    __shared__ float w_s[NSPLIT][NH];
    __shared__ float opts_s[288];
    __shared__ float rot_s[9], trans_s[3];
    const int t = threadIdx.x;
    const int q = blockIdx.x;
    const float* P0 = ws + WS_PART + (size_t)q * NSPLIT * PSTRIDE;

    if (t < NH) {
        float m0 = P0[t], m1 = P0[PSTRIDE + t];
        float M = fmaxf(m0, m1);
        float e0 = __expf(m0 - M), e1 = __expf(m1 - M);
        float denom = e0 * P0[12 + t] + e1 * P0[PSTRIDE + 12 + t];
        float inv = 1.f / denom;
        w_s[0][t] = e0 * inv; w_s[1][t] = e1 * inv;
    }
    if (t < 9) rot_s[t] = rot[q * 9 + t];
    if (t < 3) trans_s[t] = trans[q * 3 + t];
    __syncthreads();

    float* cat = ws + WS_CAT + (size_t)q * CATD;
    for (int e = t; e < 2016; e += 256) {
        int h, po;
        if (e < 192)      { h = e >> 4;          po = 24 + e; }
        else if (e < 480) { h = (e - 192) / 24;  po = 216 + (e - 192); }
        else              { h = (e - 480) >> 7;  po = 504 + (e - 480); }
        float val = w_s[0][h] * P0[po] + w_s[1][h] * P0[PSTRIDE + po];
        if (e < 192)      cat[e] = val;
        else if (e < 480) opts_s[e - 192] = val;
        else              cat[576 + (e - 480)] = val;
    }
    __syncthreads();

    if (t < 96) {   // inverse frame + norm
        int gh = t >> 3, p = t & 7;
        float gx = opts_s[gh * 24 + p * 3 + 0] - trans_s[0];
        float gy = opts_s[gh * 24 + p * 3 + 1] - trans_s[1];
        float gz = opts_s[gh * 24 + p * 3 + 2] - trans_s[2];
        float lx = rot_s[0] * gx + rot_s[3] * gy + rot_s[6] * gz;
        float ly = rot_s[1] * gx + rot_s[4] * gy + rot_s[7] * gz;
        float lz = rot_s[2] * gx + rot_s[5] * gy + rot_s[8] * gz;
        cat[192 + t] = lx;
        cat[288 + t] = ly;
        cat[384 + t] = lz;
        cat[480 + t] = sqrtf(lx * lx + ly * ly + lz * lz + 1e-8f);
    }
}

// ---------------- kernel 4: cat @ Wout + bout ----------------
__global__ __launch_bounds__(384) void k_out(
    const float* __restrict__ ws, const float* __restrict__ Wout,
    const float* __restrict__ bout, float* __restrict__ out)
{
    __shared__ float cat_s[2][192];
    const int t = threadIdx.x;
    const int n0 = blockIdx.x * 2;
    float acc[2] = {0.f, 0.f};
    for (int c0 = 0; c0 < CATD; c0 += 192) {
        __syncthreads();
        {
            int idx = t;                       // 384 threads load 2*192 elems
            cat_s[idx / 192][idx % 192] =
                ws[WS_CAT + (size_t)(n0 + idx / 192) * CATD + c0 + idx % 192];
        }
        __syncthreads();
        for (int i = 0; i < 192; i++) {
            float wv = Wout[(size_t)(c0 + i) * DS + t];
            #pragma unroll
            for (int r = 0; r < 2; r++) acc[r] += cat_s[r][i] * wv;
        }
    }
    float b = bout[t];
    #pragma unroll
    for (int r = 0; r < 2; r++) out[(size_t)(n0 + r) * DS + t] = acc[r] + b;
}

extern "C" void kernel_launch(void* const* d_in, const int* in_sizes, int n_in,
                              void* d_out, int out_size, void* d_ws, size_t ws_size,
                              hipStream_t stream)
{
    const float* s     = (const float*)d_in[0];
    const float* z     = (const float*)d_in[1];
    const float* mask  = (const float*)d_in[2];
    const float* rot   = (const float*)d_in[3];
    const float* trans = (const float*)d_in[4];
    const float* Wq    = (const float*)d_in[5];
    const float* bq    = (const float*)d_in[6];
    const float* Wkv   = (const float*)d_in[7];
    const float* bkv   = (const float*)d_in[8];
    const float* Wqp   = (const float*)d_in[9];
    const float* bqp   = (const float*)d_in[10];
    const float* Wkvp  = (const float*)d_in[11];
    const float* bkvp  = (const float*)d_in[12];
    const float* Wb    = (const float*)d_in[13];
    const float* bb    = (const float*)d_in[14];
    const float* hwt   = (const float*)d_in[15];
    const float* Wout  = (const float*)d_in[16];
    const float* bout  = (const float*)d_in[17];
    float* ws  = (float*)d_ws;
    float* out = (float*)d_out;

    hipLaunchKernelGGL(k_proj, dim3(96), dim3(256), 0, stream,
                       s, rot, trans, Wq, bq, Wkv, bkv, Wqp, bqp, Wkvp, bkvp, Wb, ws);
    hipLaunchKernelGGL(k_attn, dim3(N_RES * NSPLIT), dim3(256), 0, stream,
                       z, mask, bb, hwt, ws);
    hipLaunchKernelGGL(k_merge, dim3(N_RES), dim3(256), 0, stream,
                       rot, trans, ws);
    hipLaunchKernelGGL(k_out, dim3(384), dim3(384), 0, stream,
                       ws, Wout, bout, out);
}

// Round 9
// 414.655 us; speedup vs baseline: 5.2384x; 5.2384x over previous
//
#include <hip/hip_runtime.h>
#include <math.h>

#define N_RES 768
#define DS 384
#define DP 128
#define DH 16
#define NH 12
#define PQ 4
#define PV 8
#define HC (NH*DH)              // 192
#define CATD (NH*(DP+DH+PV*4))  // 2112
#define BK 64

typedef __attribute__((ext_vector_type(8))) short bf16x8;
typedef __attribute__((ext_vector_type(4))) short bf16x4;
typedef __attribute__((ext_vector_type(4))) float f32x4;

// ws float offsets
#define WS_Q    0                            // [768][192] f32
#define WS_KT   (WS_Q + N_RES*HC)            // [12][768][16] f32 (k-major rows of 16d)
#define WS_QP   (WS_KT + NH*N_RES*DH)        // [768][144] f32
#define WS_KPT  (WS_QP + N_RES*144)          // [12][768][12] f32
#define WS_KPSQ (WS_KPT + NH*N_RES*12)       // [12][768] f32
#define WS_VT   (WS_KPSQ + NH*N_RES)         // ushort [192][768]  V transposed bf16
#define WS_VPT  (WS_VT + NH*DH*N_RES/2)      // ushort [288][768]  VP transposed bf16
#define WS_CAT  (WS_VPT + 288*N_RES/2)       // [768][2112] f32

__device__ __forceinline__ unsigned short f2b(float f) {
    unsigned u = __float_as_uint(f);
    u += 0x7FFF + ((u >> 16) & 1);       // RNE
    return (unsigned short)(u >> 16);
}

// ---------------- kernel 1: input projections + frame apply ----------------
__global__ __launch_bounds__(256) void k_proj(
    const float* __restrict__ s, const float* __restrict__ rot,
    const float* __restrict__ trans,
    const float* __restrict__ Wq, const float* __restrict__ bq,
    const float* __restrict__ Wkv, const float* __restrict__ bkv,
    const float* __restrict__ Wqp, const float* __restrict__ bqp,
    const float* __restrict__ Wkvp, const float* __restrict__ bkvp,
    float* __restrict__ ws)
{
    __shared__ float s_s[8][DS];
    __shared__ float rq[8][NH*PQ*3];
    __shared__ float rkv[8][NH*(PQ+PV)*3];
    __shared__ float kpsq_s[8][NH];
    const int t = threadIdx.x;
    const int n0 = blockIdx.x * 8;
    unsigned short* vt  = (unsigned short*)(ws + WS_VT);
    unsigned short* vpt = (unsigned short*)(ws + WS_VPT);

    for (int idx = t; idx < 8 * DS; idx += 256)
        s_s[idx / DS][idx % DS] = s[(n0 + idx / DS) * DS + idx % DS];
    if (t < 96) kpsq_s[t / 12][t % 12] = 0.f;
    __syncthreads();

    // 1152 output columns: [Wq 192 | Wkv 384 | Wqp 144 | Wkvp 432]
    for (int j = t; j < 1152; j += 256) {
        const float* W; int col, nc; float bias;
        if (j < 192)      { W = Wq;   col = j;       nc = 192; bias = bq[col]; }
        else if (j < 576) { W = Wkv;  col = j - 192; nc = 384; bias = bkv[col]; }
        else if (j < 720) { W = Wqp;  col = j - 576; nc = 144; bias = bqp[col]; }
        else              { W = Wkvp; col = j - 720; nc = 432; bias = bkvp[col]; }
        float acc[8];
        #pragma unroll
        for (int r = 0; r < 8; r++) acc[r] = bias;
        for (int i = 0; i < DS; i++) {
            float w = W[i * nc + col];
            #pragma unroll
            for (int r = 0; r < 8; r++) acc[r] += s_s[r][i] * w;
        }
        if (j < 192) {
            #pragma unroll
            for (int r = 0; r < 8; r++) ws[WS_Q + (size_t)(n0 + r) * HC + j] = acc[r];
        } else if (j < 576) {
            int jj = j - 192, h = jj / 32, dd = jj % 32;
            if (dd < 16) {  // K -> [h][k][16] (lane-coalesced 64B rows)
                #pragma unroll
                for (int r = 0; r < 8; r++)
                    ws[WS_KT + ((size_t)h * N_RES + (n0 + r)) * 16 + dd] = acc[r];
            } else {        // V -> VT bf16 [vcol][k]
                #pragma unroll
                for (int r = 0; r < 8; r++)
                    vt[(size_t)(h * 16 + dd - 16) * N_RES + (n0 + r)] = f2b(acc[r]);
            }
        } else if (j < 720) {
            #pragma unroll
            for (int r = 0; r < 8; r++) rq[r][j - 576] = acc[r];
        } else {
            #pragma unroll
            for (int r = 0; r < 8; r++) rkv[r][j - 720] = acc[r];
        }
    }
    __syncthreads();

    // frame apply: 8 rows * (48 qp + 144 kvp) points
    for (int idx = t; idx < 8 * 192; idx += 256) {
        int r = idx / 192, pi = idx % 192;
        int n = n0 + r;
        const float* R = rot + n * 9;
        const float* T = trans + n * 3;
        if (pi < 48) {
            float x = rq[r][pi], y = rq[r][48 + pi], zc = rq[r][96 + pi];
            float* dst = ws + WS_QP + (size_t)n * 144 + pi * 3;
            dst[0] = R[0] * x + R[1] * y + R[2] * zc + T[0];
            dst[1] = R[3] * x + R[4] * y + R[5] * zc + T[1];
            dst[2] = R[6] * x + R[7] * y + R[8] * zc + T[2];
        } else {
            int p2 = pi - 48;
            float x = rkv[r][p2], y = rkv[r][144 + p2], zc = rkv[r][288 + p2];
            int h = p2 / 12, pp = p2 % 12;
            float fx = R[0] * x + R[1] * y + R[2] * zc + T[0];
            float fy = R[3] * x + R[4] * y + R[5] * zc + T[1];
            float fz = R[6] * x + R[7] * y + R[8] * zc + T[2];
            if (pp < 4) {   // k_pts -> [h][k][12] f32
                float* b = ws + WS_KPT + ((size_t)h * N_RES + n) * 12 + pp * 3;
                b[0] = fx; b[1] = fy; b[2] = fz;
                atomicAdd(&kpsq_s[r][h], fx * fx + fy * fy + fz * fz);
            } else {        // v_pts -> VPT bf16 [pcol][k], pcol = h*24 + p*3 + c
                int p = pp - 4;
                size_t b = (size_t)(h * 24 + p * 3) * N_RES + n;
                vpt[b] = f2b(fx); vpt[b + N_RES] = f2b(fy); vpt[b + 2 * N_RES] = f2b(fz);
            }
        }
    }
    __syncthreads();
    if (t < 96)   // kpsq transposed [h][k]
        ws[WS_KPSQ + (size_t)(t % 12) * N_RES + (n0 + t / 12)] = kpsq_s[t / 12][t % 12];
}

// ---------------- kernel 2: fused IPA attention with MFMA ----------------
// grid 768 (one q/block), 256 thr = 4 waves. Per BK=64 tile:
//   stage z->z_s bf16; [B1] LDS-transpose z_s->z_t + bias MFMA -> b_lds;
//   [B2] scalar logits (lane=k) + wave-local online softmax -> p_lds bf16;
//   [B3] MFMA output GEMMs (o_pair from z_t; o,o_pts dense from global VT/VPT).
__global__ __launch_bounds__(256) void k_attn(
    const float* __restrict__ zg, const float* __restrict__ mask,
    const float* __restrict__ rot, const float* __restrict__ trans,
    const float* __restrict__ Wb, const float* __restrict__ bb,
    const float* __restrict__ hweights,
    float* __restrict__ ws)
{
    __shared__ unsigned short z_s[BK][136];    // 17.4 KB  z tile bf16 (k-major)
    __shared__ unsigned short z_t[DP][76];     // 19.5 KB  z tile bf16 (c-major)
    __shared__ unsigned short p_lds[16][72];   // 2.3 KB   P bf16 (rows 12-15 zero)
    __shared__ unsigned short Wbt[16][136];    // 4.4 KB   Wb^T * sqrt(1/3) bf16
    __shared__ float b_lds[BK][13];            // 3.3 KB   bias redistribution
    __shared__ float q_s[HC];
    __shared__ float qph_s[144];
    __shared__ float r_s[16], inv_s[16];
    __shared__ float opts_s[288];
    __shared__ float rot_s[9], trans_s[3];

    const int t = threadIdx.x;
    const int lane = t & 63;
    const int w = t >> 6;         // wave 0..3
    const int l15 = lane & 15;
    const int g = lane >> 4;      // 0..3
    const int h0 = 3 * w;
    const int q = blockIdx.x;

    const float* zq = zg + (size_t)q * N_RES * DP;
    const unsigned short* VT  = (const unsigned short*)(ws + WS_VT);
    const unsigned short* VPT = (const unsigned short*)(ws + WS_VPT);

    // ---- prologue ----
    for (int i = t; i < HC; i += 256)
        q_s[i] = ws[WS_Q + (size_t)q * HC + i] * 0.1443375673f;        // sqrt(1/48)
    for (int i = t; i < 144; i += 256) {
        float hwv = log1pf(expf(hweights[i / 12])) * 0.1360827635f;    // softplus*sqrt(1/54)
        qph_s[i] = ws[WS_QP + (size_t)q * 144 + i] * hwv;
    }
    for (int i = t; i < 16 * 136; i += 256) {
        int h = i / 136, c = i % 136;
        Wbt[h][c] = (h < 12 && c < 128) ? f2b(Wb[c * NH + h] * 0.5773502692f) : 0;
    }
    for (int i = t; i < 16 * 72; i += 256) p_lds[i / 72][i % 72] = 0;
    if (t < 16) { r_s[t] = 1.f; inv_s[t] = 1.f; }
    if (t < 9) rot_s[t] = rot[q * 9 + t];
    if (t < 3) trans_s[t] = trans[q * 3 + t];

    float bbv[3], hw3[3];
    #pragma unroll
    for (int hl = 0; hl < 3; hl++) {
        bbv[hl] = bb[h0 + hl] * 0.5773502692f;
        hw3[hl] = log1pf(expf(hweights[h0 + hl])) * 0.1360827635f;
    }
    float m_run[3], ssum[3];
    #pragma unroll
    for (int hl = 0; hl < 3; hl++) { m_run[hl] = -1e30f; ssum[hl] = 0.f; }

    f32x4 acc_op[2], acc_o[3], acc_pt[5];
    #pragma unroll
    for (int i = 0; i < 2; i++) acc_op[i] = (f32x4){0.f, 0.f, 0.f, 0.f};
    #pragma unroll
    for (int i = 0; i < 3; i++) acc_o[i] = (f32x4){0.f, 0.f, 0.f, 0.f};
    #pragma unroll
    for (int i = 0; i < 5; i++) acc_pt[i] = (f32x4){0.f, 0.f, 0.f, 0.f};

    __syncthreads();

    for (int kb = 0; kb < N_RES; kb += BK) {
        // ---- stage z tile (fp32 -> bf16, coalesced) ----
        {
            const float4* src = (const float4*)(zq + (size_t)kb * DP);
            #pragma unroll
            for (int i = 0; i < 8; i++) {
                int idx = i * 256 + t;
                int k = idx >> 5, c4 = idx & 31;
                float4 v = src[idx];
                unsigned u0 = (unsigned)f2b(v.x) | ((unsigned)f2b(v.y) << 16);
                unsigned u1 = (unsigned)f2b(v.z) | ((unsigned)f2b(v.w) << 16);
                *(unsigned long long*)&z_s[k][c4 * 4] =
                    (unsigned long long)u0 | ((unsigned long long)u1 << 32);
            }
        }
        __syncthreads();   // B1

        // ---- LDS transpose z_s -> z_t ----
        {
            int c = t >> 1, kh = (t & 1) * 32;
            #pragma unroll
            for (int i = 0; i < 32; i++) z_t[c][kh + i] = z_s[kh + i][c];
        }
        // ---- bias MFMA: D[h][k-subtile w] = Wbt . z_s ----
        {
            f32x4 bacc = (f32x4){0.f, 0.f, 0.f, 0.f};
            #pragma unroll
            for (int kc = 0; kc < 4; kc++) {
                bf16x8 a = *(bf16x8*)&Wbt[l15][kc * 32 + g * 8];
                bf16x8 b = *(bf16x8*)&z_s[w * 16 + l15][kc * 32 + g * 8];
                bacc = __builtin_amdgcn_mfma_f32_16x16x32_bf16(a, b, bacc, 0, 0, 0);
            }
            #pragma unroll
            for (int r = 0; r < 4; r++) {
                int h = g * 4 + r;
                if (h < 12) b_lds[w * 16 + l15][h] = bacc[r];
            }
        }
        __syncthreads();   // B2

        // ---- scalar logits + online softmax (lane = k owner, 3 heads/wave) ----
        {
            const int kk = kb + lane;
            float mval = mask[(size_t)q * N_RES + kk];
            #pragma unroll
            for (int hl = 0; hl < 3; hl++) {
                int gh = h0 + hl;
                float dot = b_lds[lane][gh] + bbv[hl] + mval
                          - 0.5f * hw3[hl] * ws[WS_KPSQ + (size_t)gh * N_RES + kk];
                const float4* kt = (const float4*)(ws + WS_KT + ((size_t)gh * N_RES + kk) * 16);
                const float4* qv = (const float4*)&q_s[gh * 16];
                #pragma unroll
                for (int d4 = 0; d4 < 4; d4++) {
                    float4 kv = kt[d4], qq = qv[d4];
                    dot += qq.x * kv.x + qq.y * kv.y + qq.z * kv.z + qq.w * kv.w;
                }
                const float4* kpt = (const float4*)(ws + WS_KPT + ((size_t)gh * N_RES + kk) * 12);
                const float4* qp = (const float4*)&qph_s[gh * 12];
                #pragma unroll
                for (int c4 = 0; c4 < 3; c4++) {
                    float4 kv = kpt[c4], qq = qp[c4];
                    dot += qq.x * kv.x + qq.y * kv.y + qq.z * kv.z + qq.w * kv.w;
                }
                float lm = dot;
                #pragma unroll
                for (int off = 32; off; off >>= 1) lm = fmaxf(lm, __shfl_xor(lm, off));
                float m_new = fmaxf(m_run[hl], lm);
                float rr = __expf(m_run[hl] - m_new);
                float p = __expf(dot - m_new);
                ssum[hl] = ssum[hl] * rr + p;
                m_run[hl] = m_new;
                p_lds[gh][lane] = f2b(p);
                if (lane == 0) r_s[gh] = rr;
            }
        }
        __syncthreads();   // B3

        // ---- output GEMMs (MFMA), acc rescaled per tile by r_s[h-row] ----
        {
            bf16x8 pa0 = *(bf16x8*)&p_lds[l15][g * 8];
            bf16x8 pa1 = *(bf16x8*)&p_lds[l15][32 + g * 8];
            float rr0 = r_s[g * 4 + 0], rr1 = r_s[g * 4 + 1];
            float rr2 = r_s[g * 4 + 2], rr3 = r_s[g * 4 + 3];

            // o_pair: B = z_t (c-major)
            #pragma unroll
            for (int i = 0; i < 2; i++) {
                int ct = w * 2 + i;
                acc_op[i][0] *= rr0; acc_op[i][1] *= rr1;
                acc_op[i][2] *= rr2; acc_op[i][3] *= rr3;
                bf16x4 lo0 = *(bf16x4*)&z_t[ct * 16 + l15][g * 8];
                bf16x4 hi0 = *(bf16x4*)&z_t[ct * 16 + l15][g * 8 + 4];
                bf16x4 lo1 = *(bf16x4*)&z_t[ct * 16 + l15][32 + g * 8];
                bf16x4 hi1 = *(bf16x4*)&z_t[ct * 16 + l15][32 + g * 8 + 4];
                bf16x8 b0 = __builtin_shufflevector(lo0, hi0, 0, 1, 2, 3, 4, 5, 6, 7);
                bf16x8 b1 = __builtin_shufflevector(lo1, hi1, 0, 1, 2, 3, 4, 5, 6, 7);
                acc_op[i] = __builtin_amdgcn_mfma_f32_16x16x32_bf16(pa0, b0, acc_op[i], 0, 0, 0);
                acc_op[i] = __builtin_amdgcn_mfma_f32_16x16x32_bf16(pa1, b1, acc_op[i], 0, 0, 0);
            }
            // o: B = VT bf16 global (dense, diagonal kept at write)
            #pragma unroll
            for (int i = 0; i < 3; i++) {
                int vtile = w * 3 + i;
                acc_o[i][0] *= rr0; acc_o[i][1] *= rr1;
                acc_o[i][2] *= rr2; acc_o[i][3] *= rr3;
                const unsigned short* vr = VT + (size_t)(vtile * 16 + l15) * N_RES + kb;
                bf16x8 b0 = *(const bf16x8*)&vr[g * 8];
                bf16x8 b1 = *(const bf16x8*)&vr[32 + g * 8];
                acc_o[i] = __builtin_amdgcn_mfma_f32_16x16x32_bf16(pa0, b0, acc_o[i], 0, 0, 0);
                acc_o[i] = __builtin_amdgcn_mfma_f32_16x16x32_bf16(pa1, b1, acc_o[i], 0, 0, 0);
            }
            // o_pts: B = VPT bf16 global
            #pragma unroll
            for (int i = 0; i < 5; i++) {
                int pt = w * 5 + i;
                if (pt < 18) {
                    acc_pt[i][0] *= rr0; acc_pt[i][1] *= rr1;
                    acc_pt[i][2] *= rr2; acc_pt[i][3] *= rr3;
                    const unsigned short* vr = VPT + (size_t)(pt * 16 + l15) * N_RES + kb;
                    bf16x8 b0 = *(const bf16x8*)&vr[g * 8];
                    bf16x8 b1 = *(const bf16x8*)&vr[32 + g * 8];
                    acc_pt[i] = __builtin_amdgcn_mfma_f32_16x16x32_bf16(pa0, b0, acc_pt[i], 0, 0, 0);
                    acc_pt[i] = __builtin_amdgcn_mfma_f32_16x16x32_bf16(pa1, b1, acc_pt[i], 0, 0, 0);
                }
            }
        }
    }

    // ---- denominators ----
    #pragma unroll
    for (int hl = 0; hl < 3; hl++) {
        float sv = ssum[hl];
        #pragma unroll
        for (int off = 32; off; off >>= 1) sv += __shfl_xor(sv, off);
        if (lane == 0) inv_s[h0 + hl] = 1.f / sv;
    }
    __syncthreads();

    float* cat = ws + WS_CAT + (size_t)q * CATD;
    // o_pair: D[h][c]
    #pragma unroll
    for (int i = 0; i < 2; i++) {
        int c = (w * 2 + i) * 16 + l15;
        #pragma unroll
        for (int r = 0; r < 4; r++) {
            int h = g * 4 + r;
            if (h < 12) cat[576 + h * 128 + c] = acc_op[i][r] * inv_s[h];
        }
    }
    // o: keep diagonal h == vtile
    #pragma unroll
    for (int i = 0; i < 3; i++) {
        int vtile = w * 3 + i;
        #pragma unroll
        for (int r = 0; r < 4; r++) {
            if ((vtile & 3) == r && (vtile >> 2) == g)
                cat[vtile * 16 + l15] = acc_o[i][r] * inv_s[vtile];
        }
    }
    // o_pts: keep h == pcol/24 -> opts_s
    #pragma unroll
    for (int i = 0; i < 5; i++) {
        int pt = w * 5 + i;
        if (pt < 18) {
            int pcol = pt * 16 + l15;
            int hown = pcol / 24;
            #pragma unroll
            for (int r = 0; r < 4; r++) {
                if (hown == g * 4 + r)
                    opts_s[pcol] = acc_pt[i][r] * inv_s[hown];
            }
        }
    }
    __syncthreads();

    // inverse frame + norm: t<96 -> (head, point)
    if (t < 96) {
        int gh = t >> 3, p = t & 7;
        float gx = opts_s[gh * 24 + p * 3 + 0] - trans_s[0];
        float gy = opts_s[gh * 24 + p * 3 + 1] - trans_s[1];
        float gz = opts_s[gh * 24 + p * 3 + 2] - trans_s[2];
        float lx = rot_s[0] * gx + rot_s[3] * gy + rot_s[6] * gz;
        float ly = rot_s[1] * gx + rot_s[4] * gy + rot_s[7] * gz;
        float lz = rot_s[2] * gx + rot_s[5] * gy + rot_s[8] * gz;
        cat[192 + t] = lx;
        cat[288 + t] = ly;
        cat[384 + t] = lz;
        cat[480 + t] = sqrtf(lx * lx + ly * ly + lz * lz + 1e-8f);
    }
}

// ---------------- kernel 3: cat @ Wout + bout ----------------
__global__ __launch_bounds__(384) void k_out(
    const float* __restrict__ ws, const float* __restrict__ Wout,
    const float* __restrict__ bout, float* __restrict__ out)
{
    __shared__ float cat_s[2][192];
    const int t = threadIdx.x;
    const int n0 = blockIdx.x * 2;
    float acc[2] = {0.f, 0.f};
    for (int c0 = 0; c0 < CATD; c0 += 192) {
        __syncthreads();
        {
            int idx = t;
            cat_s[idx / 192][idx % 192] =
                ws[WS_CAT + (size_t)(n0 + idx / 192) * CATD + c0 + idx % 192];
        }
        __syncthreads();
        for (int i = 0; i < 192; i++) {
            float wv = Wout[(size_t)(c0 + i) * DS + t];
            #pragma unroll
            for (int r = 0; r < 2; r++) acc[r] += cat_s[r][i] * wv;
        }
    }
    float b = bout[t];
    #pragma unroll
    for (int r = 0; r < 2; r++) out[(size_t)(n0 + r) * DS + t] = acc[r] + b;
}

extern "C" void kernel_launch(void* const* d_in, const int* in_sizes, int n_in,
                              void* d_out, int out_size, void* d_ws, size_t ws_size,
                              hipStream_t stream)
{
    const float* s     = (const float*)d_in[0];
    const float* z     = (const float*)d_in[1];
    const float* mask  = (const float*)d_in[2];
    const float* rot   = (const float*)d_in[3];
    const float* trans = (const float*)d_in[4];
    const float* Wq    = (const float*)d_in[5];
    const float* bq    = (const float*)d_in[6];
    const float* Wkv   = (const float*)d_in[7];
    const float* bkv   = (const float*)d_in[8];
    const float* Wqp   = (const float*)d_in[9];
    const float* bqp   = (const float*)d_in[10];
    const float* Wkvp  = (const float*)d_in[11];
    const float* bkvp  = (const float*)d_in[12];
    const float* Wb    = (const float*)d_in[13];
    const float* bb    = (const float*)d_in[14];
    const float* hwt   = (const float*)d_in[15];
    const float* Wout  = (const float*)d_in[16];
    const float* bout  = (const float*)d_in[17];
    float* ws  = (float*)d_ws;
    float* out = (float*)d_out;

    hipLaunchKernelGGL(k_proj, dim3(96), dim3(256), 0, stream,
                       s, rot, trans, Wq, bq, Wkv, bkv, Wqp, bqp, Wkvp, bkvp, ws);
    hipLaunchKernelGGL(k_attn, dim3(N_RES), dim3(256), 0, stream,
                       z, mask, rot, trans, Wb, bb, hwt, ws);
    hipLaunchKernelGGL(k_out, dim3(384), dim3(384), 0, stream,
                       ws, Wout, bout, out);
}